// Round 6
// baseline (317.947 us; speedup 1.0000x reference)
//
#include <hip/hip_runtime.h>
#include <stdint.h>

#define N_NODES   50000
#define N_EDGES   800000
#define IN_DIM    128
#define OUT_DIM   128
#define NUM_RELS  8
#define THREADS   256

typedef _Float16 half_t;
typedef _Float16 half2v __attribute__((ext_vector_type(2)));
typedef _Float16 half4v __attribute__((ext_vector_type(4)));
typedef _Float16 half8 __attribute__((ext_vector_type(8)));
typedef float floatx4 __attribute__((ext_vector_type(4)));

// ============ plan ============
// 1. y2[n][r*128+c] = feat[n] @ W[r]  -- MFMA GEMM, 4 m-tiles/block, pipelined feat prefetch
// 2. counting-sort edges by dst (hist -> single-block scan -> scatter)
// 3. wave per dst, paired-edge loads: out[d] = sum_e w_e * y2[base_e : +128]

#define NBINS3    N_NODES                         // 50000

// ws layout (bytes) -- identical to round-5 proven budget
#define WS_Y2     0                               // y2   : 50000 x 1024 f16 (102,400,000)
#define WS_OFF    102400000                       // off  : 50001 i32 (pad to 200,064)
#define WS_WT     102600064                       // WT   : 1024 x 128 f16 (262,144)
#define WS_BASE   102862208                       // base : N_EDGES i32 (3,200,000)
#define WS_WGT    106062208                       // wgt  : N_EDGES f16 (1,600,000)
#define WS_HIST   107662208                       // hist/cursors : 50000 i32 (200,000)
#define WS_NEED   (size_t)107862464

// ---- fused: WT transpose-convert + dst histogram
__global__ void prep_hist_kernel(const float* __restrict__ rel_emb, half_t* __restrict__ WT,
                                 const int* __restrict__ dst, int* __restrict__ hist) {
    int b = blockIdx.x;
    if (b < 512) {                                 // 512*256 = 131072 = 8*128*128 exactly
        int t = b * 256 + threadIdx.x;
        int r = t >> 14, k = (t >> 7) & 127, n = t & 127;
        WT[(size_t)((r << 7) | n) * 128 + k] = (half_t)rel_emb[t];
    } else {
        int i = (b - 512) * 256 + threadIdx.x;
        if (i < N_EDGES) atomicAdd(&hist[dst[i]], 1);
    }
}

// ---- single-block fused exclusive scan over 50000 bins
__global__ __launch_bounds__(1024) void scan_all_kernel(const int* __restrict__ hist,
                                                        int* __restrict__ off,
                                                        int* __restrict__ cursors) {
    __shared__ int sh[1024];
    const int t = threadIdx.x;
    int carry = 0;
    for (int c = 0; c < 13; c++) {                 // 13 * 4096 = 53248 >= 50000
        int i0 = c * 4096 + t * 4;
        int v0 = (i0     < NBINS3) ? hist[i0]     : 0;
        int v1 = (i0 + 1 < NBINS3) ? hist[i0 + 1] : 0;
        int v2 = (i0 + 2 < NBINS3) ? hist[i0 + 2] : 0;
        int v3 = (i0 + 3 < NBINS3) ? hist[i0 + 3] : 0;
        int s = v0 + v1 + v2 + v3;
        sh[t] = s; __syncthreads();
        for (int o = 1; o < 1024; o <<= 1) {
            int x = (t >= o) ? sh[t - o] : 0;
            __syncthreads();
            sh[t] += x;
            __syncthreads();
        }
        int run = carry + sh[t] - s;
        if (i0     < NBINS3) { off[i0]     = run; cursors[i0]     = run; } run += v0;
        if (i0 + 1 < NBINS3) { off[i0 + 1] = run; cursors[i0 + 1] = run; } run += v1;
        if (i0 + 2 < NBINS3) { off[i0 + 2] = run; cursors[i0 + 2] = run; } run += v2;
        if (i0 + 3 < NBINS3) { off[i0 + 3] = run; cursors[i0 + 3] = run; }
        carry += sh[1023];
        __syncthreads();                           // protect sh before next chunk write
    }
    if (t == 0) off[NBINS3] = N_EDGES;
}

// scatter edge records: base = src*1024 + rel*128 (y2 row offset), w as f16
__global__ void scatter3_kernel(const int* __restrict__ dst, const int* __restrict__ src,
                                const int* __restrict__ rel, const float* __restrict__ ew,
                                int* __restrict__ cursors, int* __restrict__ base,
                                half_t* __restrict__ wgt) {
    int i = blockIdx.x * blockDim.x + threadIdx.x;
    if (i < N_EDGES) {
        int pos = atomicAdd(&cursors[dst[i]], 1);
        base[pos] = src[i] * 1024 + rel[i] * 128;
        wgt[pos] = (half_t)ew[i];
    }
}

// ---- GEMM: y2[50000 x 1024] = f16(feat) @ WT^T
// A = WT (M = out-col), B = feat (N = node).  Ws chunk-XOR swizzled in LDS, reused
// across 4 m-tiles per block; feat loads for tile i+1 issued before MFMA of tile i.
template<bool GUARD>
__device__ __forceinline__ void load_feat(const float* __restrict__ feat, int wm0,
                                          int q, int l16, float4 fr[2][4][2]) {
    #pragma unroll
    for (int ms = 0; ms < 2; ms++) {
        int node = wm0 + ms * 16 + l16;
        const float* fb = feat + (size_t)node * 128 + q * 8;
        bool ok = !GUARD || node < N_NODES;
        #pragma unroll
        for (int kk = 0; kk < 4; kk++)
            #pragma unroll
            for (int hh = 0; hh < 2; hh++) {
                float4 v = {0.f, 0.f, 0.f, 0.f};
                if (ok) v = *(const float4*)(fb + kk * 32 + hh * 4);
                fr[ms][kk][hh] = v;
            }
    }
}

template<bool GUARD>
__device__ __forceinline__ void gemm_mloop(const float* __restrict__ feat,
                                           const half_t* __restrict__ Ws,
                                           half_t* __restrict__ y2,
                                           int msup, int n0, int wave, int lane,
                                           float4 fr[2][4][2]) {
    const int q = lane >> 4, l16 = lane & 15;
    #pragma unroll
    for (int mi = 0; mi < 4; mi++) {
        const int wm0 = msup * 512 + mi * 128 + wave * 32;
        // convert in-flight loads to B-fragments
        half8 bf[2][4];
        #pragma unroll
        for (int ms = 0; ms < 2; ms++)
            #pragma unroll
            for (int kk = 0; kk < 4; kk++) {
                half8 hb;
                hb[0] = (half_t)fr[ms][kk][0].x; hb[1] = (half_t)fr[ms][kk][0].y;
                hb[2] = (half_t)fr[ms][kk][0].z; hb[3] = (half_t)fr[ms][kk][0].w;
                hb[4] = (half_t)fr[ms][kk][1].x; hb[5] = (half_t)fr[ms][kk][1].y;
                hb[6] = (half_t)fr[ms][kk][1].z; hb[7] = (half_t)fr[ms][kk][1].w;
                bf[ms][kk] = hb;
            }
        // issue next tile's loads; they fly during MFMA + stores
        if (mi < 3) load_feat<GUARD>(feat, wm0 + 128, q, l16, fr);

        floatx4 acc[8][2];
        #pragma unroll
        for (int nt = 0; nt < 8; nt++) {
            acc[nt][0] = (floatx4){0.f, 0.f, 0.f, 0.f};
            acc[nt][1] = (floatx4){0.f, 0.f, 0.f, 0.f};
        }
        #pragma unroll
        for (int kk = 0; kk < 4; kk++) {
            int phys = (kk * 4 + q) ^ (l16 & 7);
            #pragma unroll
            for (int nt = 0; nt < 8; nt++) {
                half8 a = *(const half8*)(Ws + (nt * 16 + l16) * 128 + phys * 8);
                acc[nt][0] = __builtin_amdgcn_mfma_f32_16x16x32_f16(a, bf[0][kk], acc[nt][0], 0, 0, 0);
                acc[nt][1] = __builtin_amdgcn_mfma_f32_16x16x32_f16(a, bf[1][kk], acc[nt][1], 0, 0, 0);
            }
        }
        // D: col(l16)=node, rows(q*4+reg)=4 consecutive out-cols -> packed half4 stores
        #pragma unroll
        for (int nt = 0; nt < 8; nt++)
            #pragma unroll
            for (int ms = 0; ms < 2; ms++) {
                int node = wm0 + ms * 16 + l16;
                int nn = n0 + nt * 16 + q * 4;
                if (!GUARD || node < N_NODES) {
                    half4v hv;
                    hv[0] = (half_t)acc[nt][ms][0]; hv[1] = (half_t)acc[nt][ms][1];
                    hv[2] = (half_t)acc[nt][ms][2]; hv[3] = (half_t)acc[nt][ms][3];
                    *(half4v*)(y2 + (size_t)node * 1024 + nn) = hv;
                }
            }
    }
}

#define GY_BLOCKS 784   // 98 m-supertiles (4 x 128 nodes) x 8 n-chunks
__global__ __launch_bounds__(THREADS) void gemm_y_kernel(
    const float* __restrict__ feat, const half_t* __restrict__ WT,
    half_t* __restrict__ y2) {
    __shared__ half_t Ws[128 * 128];               // 32 KB, swizzled
    int bid = blockIdx.x;
    int work = (bid & 7) * 98 + (bid >> 3);        // XCD-contiguous m-supertiles
    int msup = work >> 3, nchunk = work & 7;
    const int n0 = nchunk * 128;
    const int t = threadIdx.x;
    const int wave = t >> 6, lane = t & 63;
    const int q = lane >> 4, l16 = lane & 15;

    float4 fr[2][4][2];
    bool guard = (msup == 97);
    // preload tile 0 (in flight during staging + barrier)
    if (!guard) load_feat<false>(feat, msup * 512 + wave * 32, q, l16, fr);
    else        load_feat<true>(feat, msup * 512 + wave * 32, q, l16, fr);

    // stage WT chunk: 128 rows x 16 chunks of 8 halfs, chunk-XOR swizzle
    for (int i = t; i < 2048; i += THREADS) {
        int row = i >> 4, lc = i & 15;
        int phys = lc ^ (row & 7);
        *(uint4*)&Ws[row * 128 + phys * 8] =
            *(const uint4*)(WT + (size_t)(n0 + row) * 128 + lc * 8);
    }
    __syncthreads();

    if (!guard) gemm_mloop<false>(feat, Ws, y2, msup, n0, wave, lane, fr);
    else        gemm_mloop<true>(feat, Ws, y2, msup, n0, wave, lane, fr);
}

// ---- wave per dst, paired-edge loads (2 rows per instr), unroll 4 pairs
__global__ __launch_bounds__(THREADS) void gather_kernel(
    const half_t* __restrict__ y2, const int* __restrict__ base,
    const half_t* __restrict__ wgt, const int* __restrict__ off,
    float* __restrict__ out) {
    int g = blockIdx.x * 4 + (threadIdx.x >> 6);
    int lane = threadIdx.x & 63;
    int h = lane >> 5;                 // which edge of the pair
    int c4 = (lane & 31) * 4;          // 4 cols per lane
    const half_t* yb = y2 + c4;
    int beg = off[g], end = off[g + 1];
    float a0 = 0.f, a1 = 0.f, a2 = 0.f, a3 = 0.f;
    int e = beg;
    for (; e + 8 <= end; e += 8) {
        int b0 = base[e + h],     b1 = base[e + 2 + h];
        int b2 = base[e + 4 + h], b3 = base[e + 6 + h];
        half4v v0 = *(const half4v*)(yb + b0);
        half4v v1 = *(const half4v*)(yb + b1);
        half4v v2 = *(const half4v*)(yb + b2);
        half4v v3 = *(const half4v*)(yb + b3);
        float w0 = (float)wgt[e + h],     w1 = (float)wgt[e + 2 + h];
        float w2 = (float)wgt[e + 4 + h], w3 = (float)wgt[e + 6 + h];
        a0 += w0 * (float)v0[0] + w1 * (float)v1[0] + w2 * (float)v2[0] + w3 * (float)v3[0];
        a1 += w0 * (float)v0[1] + w1 * (float)v1[1] + w2 * (float)v2[1] + w3 * (float)v3[1];
        a2 += w0 * (float)v0[2] + w1 * (float)v1[2] + w2 * (float)v2[2] + w3 * (float)v3[2];
        a3 += w0 * (float)v0[3] + w1 * (float)v1[3] + w2 * (float)v2[3] + w3 * (float)v3[3];
    }
    for (; e + 2 <= end; e += 2) {
        int b = base[e + h];
        float w = (float)wgt[e + h];
        half4v v = *(const half4v*)(yb + b);
        a0 += w * (float)v[0]; a1 += w * (float)v[1];
        a2 += w * (float)v[2]; a3 += w * (float)v[3];
    }
    if (e < end && h == 0) {
        int b = base[e];
        float w = (float)wgt[e];
        half4v v = *(const half4v*)(yb + b);
        a0 += w * (float)v[0]; a1 += w * (float)v[1];
        a2 += w * (float)v[2]; a3 += w * (float)v[3];
    }
    a0 += __shfl_xor(a0, 32); a1 += __shfl_xor(a1, 32);
    a2 += __shfl_xor(a2, 32); a3 += __shfl_xor(a3, 32);
    if (h == 0) {
        float4 o; o.x = a0; o.y = a1; o.z = a2; o.w = a3;
        *(float4*)(out + (size_t)g * 128 + c4) = o;
    }
}

// ---- fallback (tiny ws): wave-per-edge direct with atomics
__global__ void naive_kernel(const float* __restrict__ feat, const float* __restrict__ rel_emb,
                             const float* __restrict__ ew, const int* __restrict__ src,
                             const int* __restrict__ dst, const int* __restrict__ rel,
                             float* __restrict__ out) {
    int wave = (blockIdx.x * blockDim.x + threadIdx.x) >> 6;
    int lane = threadIdx.x & 63;
    if (wave >= N_EDGES) return;
    const float* f = feat + (size_t)src[wave] * IN_DIM;
    const float* W = rel_emb + (size_t)rel[wave] * IN_DIM * OUT_DIM;
    float w = ew[wave];
    float a0 = 0.f, a1 = 0.f;
    for (int k = 0; k < IN_DIM; k++) {
        float fv = f[k];
        a0 += fv * W[k * OUT_DIM + lane];
        a1 += fv * W[k * OUT_DIM + 64 + lane];
    }
    int d = dst[wave];
    atomicAdd(&out[(size_t)d * OUT_DIM + lane], a0 * w);
    atomicAdd(&out[(size_t)d * OUT_DIM + 64 + lane], a1 * w);
}

extern "C" void kernel_launch(void* const* d_in, const int* in_sizes, int n_in,
                              void* d_out, int out_size, void* d_ws, size_t ws_size,
                              hipStream_t stream) {
    const float* feat    = (const float*)d_in[0];
    const float* rel_emb = (const float*)d_in[1];
    const float* ew      = (const float*)d_in[2];
    const int*   src     = (const int*)d_in[3];
    const int*   dst     = (const int*)d_in[4];
    const int*   rel     = (const int*)d_in[5];
    float* out = (float*)d_out;

    const int eb = (N_EDGES + THREADS - 1) / THREADS;   // 3125

    if (ws_size >= WS_NEED) {
        char* ws = (char*)d_ws;
        half_t* y2    = (half_t*)(ws + WS_Y2);
        int*    off   = (int*)(ws + WS_OFF);
        half_t* WT    = (half_t*)(ws + WS_WT);
        int*    basep = (int*)(ws + WS_BASE);
        half_t* wgt   = (half_t*)(ws + WS_WGT);
        int*    hist  = (int*)(ws + WS_HIST);

        hipMemsetAsync(hist, 0, (size_t)NBINS3 * 4, stream);
        prep_hist_kernel<<<512 + eb, THREADS, 0, stream>>>(rel_emb, WT, dst, hist);
        gemm_y_kernel<<<GY_BLOCKS, THREADS, 0, stream>>>(feat, WT, y2);
        scan_all_kernel<<<1, 1024, 0, stream>>>(hist, off, hist);   // in-place -> cursors
        scatter3_kernel<<<eb, THREADS, 0, stream>>>(dst, src, rel, ew, hist, basep, wgt);
        gather_kernel<<<N_NODES / 4, THREADS, 0, stream>>>(y2, basep, wgt, off, out);
    } else {
        hipMemsetAsync(d_out, 0, (size_t)out_size * sizeof(float), stream);
        const long long total = (long long)N_EDGES * 64;
        const int blocks = (int)((total + THREADS - 1) / THREADS);
        naive_kernel<<<blocks, THREADS, 0, stream>>>(feat, rel_emb, ew, src, dst, rel, out);
    }
}

// Round 7
// 257.307 us; speedup vs baseline: 1.2357x; 1.2357x over previous
//
#include <hip/hip_runtime.h>
#include <stdint.h>

#define N_NODES   50000
#define N_EDGES   800000
#define IN_DIM    128
#define OUT_DIM   128
#define NUM_RELS  8
#define THREADS   256

typedef _Float16 half_t;
typedef _Float16 half2v __attribute__((ext_vector_type(2)));
typedef _Float16 half4v __attribute__((ext_vector_type(4)));
typedef _Float16 half8 __attribute__((ext_vector_type(8)));
typedef float floatx4 __attribute__((ext_vector_type(4)));

// ============ plan ============
// 1. y2[n][r*128+c] = feat[n] @ W[r]  -- MFMA GEMM, Ws in LDS, coalesced epilogue via LDS transpose
// 2. counting-sort edges by dst; records (base = src*1024+rel*128, w f16)
// 3. wave per dst, unroll-8: out[d] = sum_e w_e * y2[base_e : +128]  (no atomics)

#define NBINS3    N_NODES                         // 50000
#define NB3       ((NBINS3 + 1023) / 1024)        // 49

// ws layout (bytes) -- round-5 proven budget
#define WS_Y2     0                               // y2   : 50000 x 1024 f16 (102,400,000)
#define WS_OFF    102400000                       // off  : 50001 i32 (pad to 200,064)
#define WS_WT     102600064                       // WT   : 1024 x 128 f16 (262,144)
#define WS_BASE   102862208                       // base : N_EDGES i32 (3,200,000)
#define WS_WGT    106062208                       // wgt  : N_EDGES f16 (1,600,000)
#define WS_HIST   107662208                       // hist/cursors : 50000 i32 (200,000)
#define WS_BSUM   107862208                       // bsum : 49 i32
#define WS_NEED   (size_t)107862464

// ---- fused: WT transpose-convert + dst histogram
__global__ void prep_hist_kernel(const float* __restrict__ rel_emb, half_t* __restrict__ WT,
                                 const int* __restrict__ dst, int* __restrict__ hist) {
    int b = blockIdx.x;
    if (b < 512) {                                 // 512*256 = 131072 = 8*128*128 exactly
        int t = b * 256 + threadIdx.x;
        int r = t >> 14, k = (t >> 7) & 127, n = t & 127;
        WT[(size_t)((r << 7) | n) * 128 + k] = (half_t)rel_emb[t];
    } else {
        int i = (b - 512) * 256 + threadIdx.x;
        if (i < N_EDGES) atomicAdd(&hist[dst[i]], 1);
    }
}

__global__ void scan1_kernel(const int* __restrict__ hist, int* __restrict__ bsum) {
    __shared__ int sh[256];
    int b = blockIdx.x, t = threadIdx.x;
    int i0 = b * 1024 + t * 4;
    int s = 0;
    #pragma unroll
    for (int j = 0; j < 4; j++) { int idx = i0 + j; if (idx < NBINS3) s += hist[idx]; }
    sh[t] = s; __syncthreads();
    for (int o = 128; o > 0; o >>= 1) { if (t < o) sh[t] += sh[t + o]; __syncthreads(); }
    if (t == 0) bsum[b] = sh[0];
}

__global__ void scan2_kernel(int* __restrict__ bsum, int* __restrict__ off) {
    __shared__ int sh[64];
    int t = threadIdx.x;
    int v = (t < NB3) ? bsum[t] : 0;
    sh[t] = v; __syncthreads();
    for (int o = 1; o < 64; o <<= 1) {
        int x = (t >= o) ? sh[t - o] : 0;
        __syncthreads();
        sh[t] += x;
        __syncthreads();
    }
    if (t < NB3) bsum[t] = sh[t] - v;
    if (t == 0) off[NBINS3] = N_EDGES;
}

__global__ void scan3_kernel(const int* __restrict__ hist, const int* __restrict__ boff,
                             int* __restrict__ off, int* __restrict__ cursors) {
    __shared__ int sh[256];
    int b = blockIdx.x, t = threadIdx.x;
    int i0 = b * 1024 + t * 4;
    int v[4]; int s = 0;
    #pragma unroll
    for (int j = 0; j < 4; j++) { int idx = i0 + j; v[j] = (idx < NBINS3) ? hist[idx] : 0; s += v[j]; }
    sh[t] = s; __syncthreads();
    for (int o = 1; o < 256; o <<= 1) {
        int x = (t >= o) ? sh[t - o] : 0;
        __syncthreads();
        sh[t] += x;
        __syncthreads();
    }
    int run = sh[t] - s + boff[b];
    #pragma unroll
    for (int j = 0; j < 4; j++) {
        int idx = i0 + j;
        if (idx < NBINS3) { off[idx] = run; cursors[idx] = run; }
        run += v[j];
    }
}

__global__ void scatter3_kernel(const int* __restrict__ dst, const int* __restrict__ src,
                                const int* __restrict__ rel, const float* __restrict__ ew,
                                int* __restrict__ cursors, int* __restrict__ base,
                                half_t* __restrict__ wgt) {
    int i = blockIdx.x * blockDim.x + threadIdx.x;
    if (i < N_EDGES) {
        int pos = atomicAdd(&cursors[dst[i]], 1);
        base[pos] = src[i] * 1024 + rel[i] * 128;
        wgt[pos] = (half_t)ew[i];
    }
}

// ---- GEMM: y2[50000 x 1024] = f16(feat) @ WT^T
// A = WT (M = out-col), B = feat (N = node).  Ws chunk-XOR swizzled in LDS.
// Epilogue: acc -> LDS transpose (Ws reused, wave-private 8KB) -> coalesced uint4 stores.
template<bool GUARD>
__device__ __forceinline__ void gemm_body(const float* __restrict__ feat,
                                          half_t* __restrict__ Ws,   // LDS
                                          half_t* __restrict__ y2,
                                          int m0, int n0, int wave, int lane) {
    const int q = lane >> 4, l16 = lane & 15;
    const int wm0 = m0 + wave * 32;

    // hoist all feat loads (in flight during stage + barrier)
    float4 fr[2][4][2];
    #pragma unroll
    for (int ms = 0; ms < 2; ms++) {
        int node = wm0 + ms * 16 + l16;
        const float* fb = feat + (size_t)node * 128 + q * 8;
        bool ok = !GUARD || node < N_NODES;
        #pragma unroll
        for (int kk = 0; kk < 4; kk++)
            #pragma unroll
            for (int h = 0; h < 2; h++) {
                float4 v = {0.f, 0.f, 0.f, 0.f};
                if (ok) v = *(const float4*)(fb + kk * 32 + h * 4);
                fr[ms][kk][h] = v;
            }
    }
    __syncthreads();   // Ws staged

    // convert to B-fragments
    half8 bf[2][4];
    #pragma unroll
    for (int ms = 0; ms < 2; ms++)
        #pragma unroll
        for (int kk = 0; kk < 4; kk++) {
            half8 hb;
            hb[0] = (half_t)fr[ms][kk][0].x; hb[1] = (half_t)fr[ms][kk][0].y;
            hb[2] = (half_t)fr[ms][kk][0].z; hb[3] = (half_t)fr[ms][kk][0].w;
            hb[4] = (half_t)fr[ms][kk][1].x; hb[5] = (half_t)fr[ms][kk][1].y;
            hb[6] = (half_t)fr[ms][kk][1].z; hb[7] = (half_t)fr[ms][kk][1].w;
            bf[ms][kk] = hb;
        }

    floatx4 acc[8][2];
    #pragma unroll
    for (int nt = 0; nt < 8; nt++)
        #pragma unroll
        for (int ms = 0; ms < 2; ms++) acc[nt][ms] = (floatx4){0.f, 0.f, 0.f, 0.f};

    #pragma unroll
    for (int kk = 0; kk < 4; kk++) {
        #pragma unroll
        for (int nt = 0; nt < 8; nt++) {
            int row = nt * 16 + l16;
            int phys = (kk * 4 + q) ^ (l16 & 7);
            half8 a = *(const half8*)(Ws + row * 128 + phys * 8);
            acc[nt][0] = __builtin_amdgcn_mfma_f32_16x16x32_f16(a, bf[0][kk], acc[nt][0], 0, 0, 0);
            acc[nt][1] = __builtin_amdgcn_mfma_f32_16x16x32_f16(a, bf[1][kk], acc[nt][1], 0, 0, 0);
        }
    }

    // ---- epilogue: transpose through Ws (dead after MFMA), coalesced stores ----
    __syncthreads();   // all waves' MFMA reads of Ws complete

    // write: wave-private rows [wave*32, wave*32+32); rotated 8B chunks (min bank occupancy)
    #pragma unroll
    for (int nt = 0; nt < 8; nt++)
        #pragma unroll
        for (int ms = 0; ms < 2; ms++) {
            int nl = wave * 32 + ms * 16 + l16;    // node_local 0..127
            int c  = nt * 4 + q;                   // logical 8B chunk 0..31
            int p  = (c + nl) & 31;                // rotation swizzle
            half4v hv;
            hv[0] = (half_t)acc[nt][ms][0]; hv[1] = (half_t)acc[nt][ms][1];
            hv[2] = (half_t)acc[nt][ms][2]; hv[3] = (half_t)acc[nt][ms][3];
            *(half4v*)(Ws + nl * 128 + p * 4) = hv;
        }
    // read back + store: 16 lanes cover one node's contiguous 256B -> uint4 fully coalesced
    #pragma unroll
    for (int i = 0; i < 8; i++) {
        int nl  = wave * 32 + i * 4 + (lane >> 4);
        int c16 = lane & 15;                       // 16B chunk within row
        int p0 = (2 * c16 + nl) & 31;
        int p1 = (2 * c16 + 1 + nl) & 31;
        uint2 lo = *(const uint2*)(Ws + nl * 128 + p0 * 4);
        uint2 hi = *(const uint2*)(Ws + nl * 128 + p1 * 4);
        int node = m0 + nl;
        if (!GUARD || node < N_NODES) {
            uint4 v; v.x = lo.x; v.y = lo.y; v.z = hi.x; v.w = hi.y;
            *(uint4*)(y2 + (size_t)node * 1024 + n0 + c16 * 8) = v;
        }
    }
}

#define GY_GRID (391 * 8)
__global__ __launch_bounds__(THREADS) void gemm_y_kernel(
    const float* __restrict__ feat, const half_t* __restrict__ WT,
    half_t* __restrict__ y2) {
    __shared__ half_t Ws[128 * 128];               // 32 KB, swizzled; reused by epilogue
    int bid = blockIdx.x;
    int work = (bid & 7) * 391 + (bid >> 3);       // XCD-contiguous m-chunks
    int mt = work >> 3, nt8 = work & 7;
    const int m0 = mt * 128, n0 = nt8 * 128;
    const int t = threadIdx.x;
    const int wave = t >> 6, lane = t & 63;

    // stage WT tile: 128 rows x 16 chunks of 8 halfs, chunk-XOR swizzle
    for (int i = t; i < 2048; i += THREADS) {
        int row = i >> 4, lc = i & 15;
        int phys = lc ^ (row & 7);
        *(uint4*)&Ws[row * 128 + phys * 8] =
            *(const uint4*)(WT + (size_t)(n0 + row) * 128 + lc * 8);
    }
    if (m0 + 128 <= N_NODES)
        gemm_body<false>(feat, Ws, y2, m0, n0, wave, lane);
    else
        gemm_body<true>(feat, Ws, y2, m0, n0, wave, lane);
}

// ---- wave per dst, unroll-8, dual accumulators (round-5 proven)
__global__ __launch_bounds__(THREADS) void gather_kernel(
    const half_t* __restrict__ y2, const int* __restrict__ base,
    const half_t* __restrict__ wgt, const int* __restrict__ off,
    float* __restrict__ out) {
    int g = blockIdx.x * 4 + (threadIdx.x >> 6);
    int lane = threadIdx.x & 63;
    int beg = off[g], end = off[g + 1];
    const half_t* yb = y2 + lane * 2;
    float ax = 0.f, ay = 0.f, cx = 0.f, cy = 0.f;
    int e = beg;
    for (; e + 8 <= end; e += 8) {
        int b0 = base[e], b1 = base[e + 1], b2 = base[e + 2], b3 = base[e + 3];
        int b4 = base[e + 4], b5 = base[e + 5], b6 = base[e + 6], b7 = base[e + 7];
        half2v v0 = *(const half2v*)(yb + b0);
        half2v v1 = *(const half2v*)(yb + b1);
        half2v v2 = *(const half2v*)(yb + b2);
        half2v v3 = *(const half2v*)(yb + b3);
        half2v v4 = *(const half2v*)(yb + b4);
        half2v v5 = *(const half2v*)(yb + b5);
        half2v v6 = *(const half2v*)(yb + b6);
        half2v v7 = *(const half2v*)(yb + b7);
        float w0 = (float)wgt[e],     w1 = (float)wgt[e + 1];
        float w2 = (float)wgt[e + 2], w3 = (float)wgt[e + 3];
        float w4 = (float)wgt[e + 4], w5 = (float)wgt[e + 5];
        float w6 = (float)wgt[e + 6], w7 = (float)wgt[e + 7];
        ax += w0 * (float)v0[0] + w1 * (float)v1[0];
        ay += w0 * (float)v0[1] + w1 * (float)v1[1];
        cx += w2 * (float)v2[0] + w3 * (float)v3[0];
        cy += w2 * (float)v2[1] + w3 * (float)v3[1];
        ax += w4 * (float)v4[0] + w5 * (float)v5[0];
        ay += w4 * (float)v4[1] + w5 * (float)v5[1];
        cx += w6 * (float)v6[0] + w7 * (float)v7[0];
        cy += w6 * (float)v6[1] + w7 * (float)v7[1];
    }
    for (; e + 2 <= end; e += 2) {
        int b0 = base[e], b1 = base[e + 1];
        float w0 = (float)wgt[e], w1 = (float)wgt[e + 1];
        half2v v0 = *(const half2v*)(yb + b0);
        half2v v1 = *(const half2v*)(yb + b1);
        ax += w0 * (float)v0[0] + w1 * (float)v1[0];
        ay += w0 * (float)v0[1] + w1 * (float)v1[1];
    }
    if (e < end) {
        int b0 = base[e];
        float w0 = (float)wgt[e];
        half2v v0 = *(const half2v*)(yb + b0);
        cx += w0 * (float)v0[0];
        cy += w0 * (float)v0[1];
    }
    float2 o; o.x = ax + cx; o.y = ay + cy;
    *(float2*)(out + (size_t)g * 128 + lane * 2) = o;
}

// ---- fallback (tiny ws): wave-per-edge direct with atomics
__global__ void naive_kernel(const float* __restrict__ feat, const float* __restrict__ rel_emb,
                             const float* __restrict__ ew, const int* __restrict__ src,
                             const int* __restrict__ dst, const int* __restrict__ rel,
                             float* __restrict__ out) {
    int wave = (blockIdx.x * blockDim.x + threadIdx.x) >> 6;
    int lane = threadIdx.x & 63;
    if (wave >= N_EDGES) return;
    const float* f = feat + (size_t)src[wave] * IN_DIM;
    const float* W = rel_emb + (size_t)rel[wave] * IN_DIM * OUT_DIM;
    float w = ew[wave];
    float a0 = 0.f, a1 = 0.f;
    for (int k = 0; k < IN_DIM; k++) {
        float fv = f[k];
        a0 += fv * W[k * OUT_DIM + lane];
        a1 += fv * W[k * OUT_DIM + 64 + lane];
    }
    int d = dst[wave];
    atomicAdd(&out[(size_t)d * OUT_DIM + lane], a0 * w);
    atomicAdd(&out[(size_t)d * OUT_DIM + 64 + lane], a1 * w);
}

extern "C" void kernel_launch(void* const* d_in, const int* in_sizes, int n_in,
                              void* d_out, int out_size, void* d_ws, size_t ws_size,
                              hipStream_t stream) {
    const float* feat    = (const float*)d_in[0];
    const float* rel_emb = (const float*)d_in[1];
    const float* ew      = (const float*)d_in[2];
    const int*   src     = (const int*)d_in[3];
    const int*   dst     = (const int*)d_in[4];
    const int*   rel     = (const int*)d_in[5];
    float* out = (float*)d_out;

    const int eb = (N_EDGES + THREADS - 1) / THREADS;   // 3125

    if (ws_size >= WS_NEED) {
        char* ws = (char*)d_ws;
        half_t* y2    = (half_t*)(ws + WS_Y2);
        int*    off   = (int*)(ws + WS_OFF);
        half_t* WT    = (half_t*)(ws + WS_WT);
        int*    basep = (int*)(ws + WS_BASE);
        half_t* wgt   = (half_t*)(ws + WS_WGT);
        int*    hist  = (int*)(ws + WS_HIST);
        int*    bsum  = (int*)(ws + WS_BSUM);

        hipMemsetAsync(hist, 0, (size_t)NBINS3 * 4, stream);
        prep_hist_kernel<<<512 + eb, THREADS, 0, stream>>>(rel_emb, WT, dst, hist);
        gemm_y_kernel<<<GY_GRID, THREADS, 0, stream>>>(feat, WT, y2);
        scan1_kernel<<<NB3, 256, 0, stream>>>(hist, bsum);
        scan2_kernel<<<1, 64, 0, stream>>>(bsum, off);
        scan3_kernel<<<NB3, 256, 0, stream>>>(hist, bsum, off, hist);  // in-place -> cursors
        scatter3_kernel<<<eb, THREADS, 0, stream>>>(dst, src, rel, ew, hist, basep, wgt);
        gather_kernel<<<N_NODES / 4, THREADS, 0, stream>>>(y2, basep, wgt, off, out);
    } else {
        hipMemsetAsync(d_out, 0, (size_t)out_size * sizeof(float), stream);
        const long long total = (long long)N_EDGES * 64;
        const int blocks = (int)((total + THREADS - 1) / THREADS);
        naive_kernel<<<blocks, THREADS, 0, stream>>>(feat, rel_emb, ew, src, dst, rel, out);
    }
}

// Round 8
// 255.432 us; speedup vs baseline: 1.2447x; 1.0073x over previous
//
#include <hip/hip_runtime.h>
#include <stdint.h>

#define N_NODES   50000
#define N_EDGES   800000
#define IN_DIM    128
#define OUT_DIM   128
#define NUM_RELS  8
#define THREADS   256

typedef _Float16 half_t;
typedef _Float16 half2v __attribute__((ext_vector_type(2)));
typedef _Float16 half4v __attribute__((ext_vector_type(4)));
typedef _Float16 half8 __attribute__((ext_vector_type(8)));
typedef float floatx4 __attribute__((ext_vector_type(4)));

// ============ plan ============
// 1. prep: WT transpose + dst histogram (2 atomics/thread)
// 2. scans -> off/cursors
// 3. FUSED launch: gemm (MFMA-bound) + scatter (latency-bound) co-resident -> pipes overlap
// 4. wave per dst, unroll-8 gather (no atomics)

#define NBINS3    N_NODES                         // 50000
#define NB3       ((NBINS3 + 1023) / 1024)        // 49

// ws layout (bytes) -- round-5/7 proven budget
#define WS_Y2     0                               // y2   : 50000 x 1024 f16 (102,400,000)
#define WS_OFF    102400000                       // off  : 50001 i32 (pad to 200,064)
#define WS_WT     102600064                       // WT   : 1024 x 128 f16 (262,144)
#define WS_BASE   102862208                       // base : N_EDGES i32 (3,200,000)
#define WS_WGT    106062208                       // wgt  : N_EDGES f16 (1,600,000)
#define WS_HIST   107662208                       // hist/cursors : 50000 i32 (200,000)
#define WS_BSUM   107862208                       // bsum : 49 i32
#define WS_NEED   (size_t)107862464

// ---- fused: WT transpose-convert + dst histogram (2 edges/thread for ILP)
#define HIST_BLOCKS ((N_EDGES + 511) / 512)       // 1563
__global__ void prep_hist_kernel(const float* __restrict__ rel_emb, half_t* __restrict__ WT,
                                 const int* __restrict__ dst, int* __restrict__ hist) {
    int b = blockIdx.x;
    if (b < 512) {                                 // 512*256 = 131072 = 8*128*128 exactly
        int t = b * 256 + threadIdx.x;
        int r = t >> 14, k = (t >> 7) & 127, n = t & 127;
        WT[(size_t)((r << 7) | n) * 128 + k] = (half_t)rel_emb[t];
    } else {
        int i = (b - 512) * 512 + threadIdx.x;
        int d0 = (i < N_EDGES) ? dst[i] : -1;
        int d1 = (i + 256 < N_EDGES) ? dst[i + 256] : -1;
        if (d0 >= 0) atomicAdd(&hist[d0], 1);
        if (d1 >= 0) atomicAdd(&hist[d1], 1);
    }
}

__global__ void scan1_kernel(const int* __restrict__ hist, int* __restrict__ bsum) {
    __shared__ int sh[256];
    int b = blockIdx.x, t = threadIdx.x;
    int i0 = b * 1024 + t * 4;
    int s = 0;
    #pragma unroll
    for (int j = 0; j < 4; j++) { int idx = i0 + j; if (idx < NBINS3) s += hist[idx]; }
    sh[t] = s; __syncthreads();
    for (int o = 128; o > 0; o >>= 1) { if (t < o) sh[t] += sh[t + o]; __syncthreads(); }
    if (t == 0) bsum[b] = sh[0];
}

__global__ void scan2_kernel(int* __restrict__ bsum, int* __restrict__ off) {
    __shared__ int sh[64];
    int t = threadIdx.x;
    int v = (t < NB3) ? bsum[t] : 0;
    sh[t] = v; __syncthreads();
    for (int o = 1; o < 64; o <<= 1) {
        int x = (t >= o) ? sh[t - o] : 0;
        __syncthreads();
        sh[t] += x;
        __syncthreads();
    }
    if (t < NB3) bsum[t] = sh[t] - v;
    if (t == 0) off[NBINS3] = N_EDGES;
}

__global__ void scan3_kernel(const int* __restrict__ hist, const int* __restrict__ boff,
                             int* __restrict__ off, int* __restrict__ cursors) {
    __shared__ int sh[256];
    int b = blockIdx.x, t = threadIdx.x;
    int i0 = b * 1024 + t * 4;
    int v[4]; int s = 0;
    #pragma unroll
    for (int j = 0; j < 4; j++) { int idx = i0 + j; v[j] = (idx < NBINS3) ? hist[idx] : 0; s += v[j]; }
    sh[t] = s; __syncthreads();
    for (int o = 1; o < 256; o <<= 1) {
        int x = (t >= o) ? sh[t - o] : 0;
        __syncthreads();
        sh[t] += x;
        __syncthreads();
    }
    int run = sh[t] - s + boff[b];
    #pragma unroll
    for (int j = 0; j < 4; j++) {
        int idx = i0 + j;
        if (idx < NBINS3) { off[idx] = run; cursors[idx] = run; }
        run += v[j];
    }
}

// ---- GEMM body: y2[50000 x 1024] = f16(feat) @ WT^T  (round-7 proven)
template<bool GUARD>
__device__ __forceinline__ void gemm_body(const float* __restrict__ feat,
                                          half_t* __restrict__ Ws,   // LDS
                                          half_t* __restrict__ y2,
                                          int m0, int n0, int wave, int lane) {
    const int q = lane >> 4, l16 = lane & 15;
    const int wm0 = m0 + wave * 32;

    // hoist all feat loads (in flight during stage + barrier)
    float4 fr[2][4][2];
    #pragma unroll
    for (int ms = 0; ms < 2; ms++) {
        int node = wm0 + ms * 16 + l16;
        const float* fb = feat + (size_t)node * 128 + q * 8;
        bool ok = !GUARD || node < N_NODES;
        #pragma unroll
        for (int kk = 0; kk < 4; kk++)
            #pragma unroll
            for (int h = 0; h < 2; h++) {
                float4 v = {0.f, 0.f, 0.f, 0.f};
                if (ok) v = *(const float4*)(fb + kk * 32 + h * 4);
                fr[ms][kk][h] = v;
            }
    }
    __syncthreads();   // Ws staged

    half8 bf[2][4];
    #pragma unroll
    for (int ms = 0; ms < 2; ms++)
        #pragma unroll
        for (int kk = 0; kk < 4; kk++) {
            half8 hb;
            hb[0] = (half_t)fr[ms][kk][0].x; hb[1] = (half_t)fr[ms][kk][0].y;
            hb[2] = (half_t)fr[ms][kk][0].z; hb[3] = (half_t)fr[ms][kk][0].w;
            hb[4] = (half_t)fr[ms][kk][1].x; hb[5] = (half_t)fr[ms][kk][1].y;
            hb[6] = (half_t)fr[ms][kk][1].z; hb[7] = (half_t)fr[ms][kk][1].w;
            bf[ms][kk] = hb;
        }

    floatx4 acc[8][2];
    #pragma unroll
    for (int nt = 0; nt < 8; nt++)
        #pragma unroll
        for (int ms = 0; ms < 2; ms++) acc[nt][ms] = (floatx4){0.f, 0.f, 0.f, 0.f};

    #pragma unroll
    for (int kk = 0; kk < 4; kk++) {
        #pragma unroll
        for (int nt = 0; nt < 8; nt++) {
            int row = nt * 16 + l16;
            int phys = (kk * 4 + q) ^ (l16 & 7);
            half8 a = *(const half8*)(Ws + row * 128 + phys * 8);
            acc[nt][0] = __builtin_amdgcn_mfma_f32_16x16x32_f16(a, bf[0][kk], acc[nt][0], 0, 0, 0);
            acc[nt][1] = __builtin_amdgcn_mfma_f32_16x16x32_f16(a, bf[1][kk], acc[nt][1], 0, 0, 0);
        }
    }

    // epilogue: transpose through Ws, coalesced uint4 stores
    __syncthreads();
    #pragma unroll
    for (int nt = 0; nt < 8; nt++)
        #pragma unroll
        for (int ms = 0; ms < 2; ms++) {
            int nl = wave * 32 + ms * 16 + l16;
            int c  = nt * 4 + q;
            int p  = (c + nl) & 31;
            half4v hv;
            hv[0] = (half_t)acc[nt][ms][0]; hv[1] = (half_t)acc[nt][ms][1];
            hv[2] = (half_t)acc[nt][ms][2]; hv[3] = (half_t)acc[nt][ms][3];
            *(half4v*)(Ws + nl * 128 + p * 4) = hv;
        }
    #pragma unroll
    for (int i = 0; i < 8; i++) {
        int nl  = wave * 32 + i * 4 + (lane >> 4);
        int c16 = lane & 15;
        int p0 = (2 * c16 + nl) & 31;
        int p1 = (2 * c16 + 1 + nl) & 31;
        uint2 lo = *(const uint2*)(Ws + nl * 128 + p0 * 4);
        uint2 hi = *(const uint2*)(Ws + nl * 128 + p1 * 4);
        int node = m0 + nl;
        if (!GUARD || node < N_NODES) {
            uint4 v; v.x = lo.x; v.y = lo.y; v.z = hi.x; v.w = hi.y;
            *(uint4*)(y2 + (size_t)node * 1024 + n0 + c16 * 8) = v;
        }
    }
}

// ---- FUSED: gemm (3128 blocks) + scatter (3125 blocks), roles alternate in groups of 8
// so each XCD gets both types; latency-bound scatter waves fill gemm's stalls (m114).
#define FUSE_BLOCKS 6256   // 391 pairs x 16
__global__ __launch_bounds__(THREADS) void fused_kernel(
    const float* __restrict__ feat, const half_t* __restrict__ WT,
    half_t* __restrict__ y2,
    const int* __restrict__ dst, const int* __restrict__ src,
    const int* __restrict__ rel, const float* __restrict__ ew,
    int* __restrict__ cursors, int* __restrict__ base, half_t* __restrict__ wgt) {
    __shared__ half_t Ws[128 * 128];               // 32 KB (gemm role only)
    const int bid = blockIdx.x;
    const int t = threadIdx.x;

    if (((bid >> 3) & 1) == 0) {
        // ---- gemm role: work preserves XCD-contiguous m-chunks (XCD = bid&7 under RR)
        int work = (bid & 7) * 391 + (bid >> 4);   // 0..3127
        int mt = work >> 3, nt8 = work & 7;
        const int m0 = mt * 128, n0 = nt8 * 128;
        const int wave = t >> 6, lane = t & 63;

        for (int i = t; i < 2048; i += THREADS) {
            int row = i >> 4, lc = i & 15;
            int phys = lc ^ (row & 7);
            *(uint4*)&Ws[row * 128 + phys * 8] =
                *(const uint4*)(WT + (size_t)(n0 + row) * 128 + lc * 8);
        }
        if (m0 + 128 <= N_NODES)
            gemm_body<false>(feat, Ws, y2, m0, n0, wave, lane);
        else
            gemm_body<true>(feat, Ws, y2, m0, n0, wave, lane);
    } else {
        // ---- scatter role
        int sblock = (bid >> 4) * 8 + (bid & 7);   // 0..3127
        if (sblock >= 3125) return;
        int i = sblock * 256 + t;                  // < 800000 exactly at 3125*256
        int pos = atomicAdd(&cursors[dst[i]], 1);
        base[pos] = src[i] * 1024 + rel[i] * 128;
        wgt[pos] = (half_t)ew[i];
    }
}

// ---- wave per dst, unroll-8, dual accumulators (round-5 proven)
__global__ __launch_bounds__(THREADS) void gather_kernel(
    const half_t* __restrict__ y2, const int* __restrict__ base,
    const half_t* __restrict__ wgt, const int* __restrict__ off,
    float* __restrict__ out) {
    int g = blockIdx.x * 4 + (threadIdx.x >> 6);
    int lane = threadIdx.x & 63;
    int beg = off[g], end = off[g + 1];
    const half_t* yb = y2 + lane * 2;
    float ax = 0.f, ay = 0.f, cx = 0.f, cy = 0.f;
    int e = beg;
    for (; e + 8 <= end; e += 8) {
        int b0 = base[e], b1 = base[e + 1], b2 = base[e + 2], b3 = base[e + 3];
        int b4 = base[e + 4], b5 = base[e + 5], b6 = base[e + 6], b7 = base[e + 7];
        half2v v0 = *(const half2v*)(yb + b0);
        half2v v1 = *(const half2v*)(yb + b1);
        half2v v2 = *(const half2v*)(yb + b2);
        half2v v3 = *(const half2v*)(yb + b3);
        half2v v4 = *(const half2v*)(yb + b4);
        half2v v5 = *(const half2v*)(yb + b5);
        half2v v6 = *(const half2v*)(yb + b6);
        half2v v7 = *(const half2v*)(yb + b7);
        float w0 = (float)wgt[e],     w1 = (float)wgt[e + 1];
        float w2 = (float)wgt[e + 2], w3 = (float)wgt[e + 3];
        float w4 = (float)wgt[e + 4], w5 = (float)wgt[e + 5];
        float w6 = (float)wgt[e + 6], w7 = (float)wgt[e + 7];
        ax += w0 * (float)v0[0] + w1 * (float)v1[0];
        ay += w0 * (float)v0[1] + w1 * (float)v1[1];
        cx += w2 * (float)v2[0] + w3 * (float)v3[0];
        cy += w2 * (float)v2[1] + w3 * (float)v3[1];
        ax += w4 * (float)v4[0] + w5 * (float)v5[0];
        ay += w4 * (float)v4[1] + w5 * (float)v5[1];
        cx += w6 * (float)v6[0] + w7 * (float)v7[0];
        cy += w6 * (float)v6[1] + w7 * (float)v7[1];
    }
    for (; e + 2 <= end; e += 2) {
        int b0 = base[e], b1 = base[e + 1];
        float w0 = (float)wgt[e], w1 = (float)wgt[e + 1];
        half2v v0 = *(const half2v*)(yb + b0);
        half2v v1 = *(const half2v*)(yb + b1);
        ax += w0 * (float)v0[0] + w1 * (float)v1[0];
        ay += w0 * (float)v0[1] + w1 * (float)v1[1];
    }
    if (e < end) {
        int b0 = base[e];
        float w0 = (float)wgt[e];
        half2v v0 = *(const half2v*)(yb + b0);
        cx += w0 * (float)v0[0];
        cy += w0 * (float)v0[1];
    }
    float2 o; o.x = ax + cx; o.y = ay + cy;
    *(float2*)(out + (size_t)g * 128 + lane * 2) = o;
}

// ---- fallback (tiny ws): wave-per-edge direct with atomics
__global__ void naive_kernel(const float* __restrict__ feat, const float* __restrict__ rel_emb,
                             const float* __restrict__ ew, const int* __restrict__ src,
                             const int* __restrict__ dst, const int* __restrict__ rel,
                             float* __restrict__ out) {
    int wave = (blockIdx.x * blockDim.x + threadIdx.x) >> 6;
    int lane = threadIdx.x & 63;
    if (wave >= N_EDGES) return;
    const float* f = feat + (size_t)src[wave] * IN_DIM;
    const float* W = rel_emb + (size_t)rel[wave] * IN_DIM * OUT_DIM;
    float w = ew[wave];
    float a0 = 0.f, a1 = 0.f;
    for (int k = 0; k < IN_DIM; k++) {
        float fv = f[k];
        a0 += fv * W[k * OUT_DIM + lane];
        a1 += fv * W[k * OUT_DIM + 64 + lane];
    }
    int d = dst[wave];
    atomicAdd(&out[(size_t)d * OUT_DIM + lane], a0 * w);
    atomicAdd(&out[(size_t)d * OUT_DIM + 64 + lane], a1 * w);
}

extern "C" void kernel_launch(void* const* d_in, const int* in_sizes, int n_in,
                              void* d_out, int out_size, void* d_ws, size_t ws_size,
                              hipStream_t stream) {
    const float* feat    = (const float*)d_in[0];
    const float* rel_emb = (const float*)d_in[1];
    const float* ew      = (const float*)d_in[2];
    const int*   src     = (const int*)d_in[3];
    const int*   dst     = (const int*)d_in[4];
    const int*   rel     = (const int*)d_in[5];
    float* out = (float*)d_out;

    if (ws_size >= WS_NEED) {
        char* ws = (char*)d_ws;
        half_t* y2    = (half_t*)(ws + WS_Y2);
        int*    off   = (int*)(ws + WS_OFF);
        half_t* WT    = (half_t*)(ws + WS_WT);
        int*    basep = (int*)(ws + WS_BASE);
        half_t* wgt   = (half_t*)(ws + WS_WGT);
        int*    hist  = (int*)(ws + WS_HIST);
        int*    bsum  = (int*)(ws + WS_BSUM);

        hipMemsetAsync(hist, 0, (size_t)NBINS3 * 4, stream);
        prep_hist_kernel<<<512 + HIST_BLOCKS, THREADS, 0, stream>>>(rel_emb, WT, dst, hist);
        scan1_kernel<<<NB3, 256, 0, stream>>>(hist, bsum);
        scan2_kernel<<<1, 64, 0, stream>>>(bsum, off);
        scan3_kernel<<<NB3, 256, 0, stream>>>(hist, bsum, off, hist);  // in-place -> cursors
        fused_kernel<<<FUSE_BLOCKS, THREADS, 0, stream>>>(feat, WT, y2, dst, src, rel, ew,
                                                          hist, basep, wgt);
        gather_kernel<<<N_NODES / 4, THREADS, 0, stream>>>(y2, basep, wgt, off, out);
    } else {
        hipMemsetAsync(d_out, 0, (size_t)out_size * sizeof(float), stream);
        const long long total = (long long)N_EDGES * 64;
        const int blocks = (int)((total + THREADS - 1) / THREADS);
        naive_kernel<<<blocks, THREADS, 0, stream>>>(feat, rel_emb, ew, src, dst, rel, out);
    }
}